// Round 1
// baseline (563.219 us; speedup 1.0000x reference)
//
#include <hip/hip_runtime.h>
#include <hip/hip_bf16.h>

// Problem constants
constexpr int Bn   = 512;   // batch
constexpr int SK   = 128;   // K seq len (== BLOCK)
constexpr int SV   = 261;   // V seq len
constexpr int Dd   = 768;   // feature dim
constexpr int Hh   = 58;    // head dim for Q/K projections
constexpr int OUTn = 512;   // output dim of Vt
constexpr int IMG  = 197;
constexpr int Mrows = Bn * SV;               // 133632
constexpr long long CTX_ELEMS = (long long)Mrows * OUTn; // 68,419,584

// ws layout (bytes)
constexpr size_t WS_U   = 0;                       // 512*768 f32 = 1,572,864
constexpr size_t WS_C   = 1572864;                 // 512 f32
constexpr size_t WS_HOT = 1574912;                 // 512 f32
constexpr size_t WS_WB  = 1576960;                 // 512*768 bf16 = 786,432 (16B aligned)

typedef __attribute__((ext_vector_type(8))) short short8;
typedef __attribute__((ext_vector_type(4))) float floatx4;

__device__ __forceinline__ short f2bf(float f) {
    return __builtin_bit_cast(short, __float2bfloat16(f));
}

__device__ __forceinline__ float sigmoidf_(float x) {
    return 1.0f / (1.0f + __expf(-x));
}

// ---------------- Kernel A: Qt + u + c per batch ----------------
__global__ void __launch_bounds__(256) qt_u_kernel(
    const float* __restrict__ Q, const float* __restrict__ Wq, const float* __restrict__ bq,
    const float* __restrict__ Wk, const float* __restrict__ bk,
    float* __restrict__ u, float* __restrict__ c)
{
    int b = blockIdx.x;
    int t = threadIdx.x, lane = t & 63, w = t >> 6; // 4 waves

    __shared__ float qrow[Dd];
    __shared__ float qt[Hh];

    for (int d = t; d < Dd; d += 256) qrow[d] = Q[b * Dd + d];
    __syncthreads();

    // Qt[h] = Q[b]·Wq[h] + bq[h] ; waves split h
    for (int h = w; h < Hh; h += 4) {
        const float* wr = Wq + (size_t)h * Dd;
        float s = 0.f;
        #pragma unroll
        for (int j = 0; j < 12; ++j) { int d = lane + 64 * j; s += qrow[d] * wr[d]; }
        #pragma unroll
        for (int off = 32; off; off >>= 1) s += __shfl_down(s, off);
        if (lane == 0) qt[h] = s + bq[h];
    }
    __syncthreads();

    // u[b,d] = sum_h qt[h]*Wk[h,d]  (coalesced over d)
    for (int d = t; d < Dd; d += 256) {
        float s = 0.f;
        #pragma unroll 2
        for (int h = 0; h < Hh; ++h) s += qt[h] * Wk[(size_t)h * Dd + d];
        u[(size_t)b * Dd + d] = s;
    }

    // c[b] = qt·bk
    if (w == 0) {
        float v = (lane < Hh) ? qt[lane] * bk[lane] : 0.f;
        #pragma unroll
        for (int off = 32; off; off >>= 1) v += __shfl_down(v, off);
        if (lane == 0) c[b] = v;
    }
}

// ---------------- Kernel B: scores -> attn (out) + hot ----------------
__global__ void __launch_bounds__(512) scores_kernel(
    const float* __restrict__ K, const float* __restrict__ u, const float* __restrict__ c,
    const float* __restrict__ Wsw, const float* __restrict__ bsw,
    float* __restrict__ attn_out, float* __restrict__ hot)
{
    int b = blockIdx.x;
    int t = threadIdx.x, lane = t & 63, w = t >> 6; // 8 waves

    __shared__ float ul[Dd];
    __shared__ float al[SK];

    for (int d = t; d < Dd; d += 512) ul[d] = u[(size_t)b * Dd + d];
    float cb = c[b];
    __syncthreads();

    const float* Kb = K + (size_t)b * SK * Dd;
    for (int k = w; k < SK; k += 8) {
        const float* kr = Kb + (size_t)k * Dd;
        float s = 0.f;
        #pragma unroll
        for (int j = 0; j < 12; ++j) { int d = lane + 64 * j; s += kr[d] * ul[d]; }
        #pragma unroll
        for (int off = 32; off; off >>= 1) s += __shfl_down(s, off);
        if (lane == 0) {
            float sc = (s + cb) * 0.0883883476483184f; // 1/sqrt(128)
            float a = sigmoidf_(sc);
            attn_out[(size_t)b * SK + k] = a;
            al[k] = a;
        }
    }
    __syncthreads();

    if (w == 0) {
        float v = al[lane] * Wsw[lane] + al[lane + 64] * Wsw[lane + 64];
        #pragma unroll
        for (int off = 32; off; off >>= 1) v += __shfl_down(v, off);
        if (lane == 0) hot[b] = sigmoidf_(v + bsw[0]);
    }
}

// ---------------- Kernel D: convert Wv f32 -> bf16, pre-swizzled tiled layout ----------------
// Layout: [nt(2)][kb(24)][16KB chunk]; chunk: col(256 local) rows of 64B (32 bf16 k's),
// 16B granule XOR-swizzled with col bits [2:1].
__global__ void __launch_bounds__(256) wv_convert(
    const float* __restrict__ Wv, unsigned short* __restrict__ wsB)
{
    int t = blockIdx.x * 256 + threadIdx.x;
    if (t >= OUTn * Dd) return;
    int col = t / Dd;
    int k   = t - col * Dd;
    int kb = k >> 5, kk = k & 31, kgrp = kk >> 3, ki = kk & 7;
    int nt = col >> 8, cl = col & 255;
    size_t byte = (size_t)nt * (24 * 16384) + (size_t)kb * 16384
                + (size_t)cl * 64 + (size_t)((kgrp ^ ((cl >> 1) & 3)) << 4) + (size_t)(ki * 2);
    wsB[byte >> 1] = (unsigned short)f2bf(Wv[t]);
}

// ---------------- Kernel C: context = scale(b,s) * (V·Wv^T + bv) ----------------
// BM=128, BN=256 (nt tile), 512 threads = 8 waves (2m x 4n), wave tile 64x64,
// mfma_f32_16x16x32_bf16, A direct from global f32 (cvt in-reg), B staged in LDS (swizzled).
__global__ void __launch_bounds__(512, 4) ctx_gemm(
    const float* __restrict__ V, const unsigned short* __restrict__ wsB,
    const float* __restrict__ bv, const float* __restrict__ hot,
    float* __restrict__ out)
{
    int bid = blockIdx.x;
    int nt = bid & 1;          // n-tile: pair adjacent blocks on same V rows for L2/L3 reuse
    int mb = bid >> 1;
    int t = threadIdx.x, lane = t & 63, w = t >> 6;
    int wm = w >> 2, wn = w & 3;           // 2 x 4 waves
    int m_base = mb * 128;

    __shared__ unsigned short btile[2][8192]; // 2 x 16KB

    const unsigned short* wsChunk = wsB + (size_t)nt * (24 * 8192); // element units

    floatx4 acc[4][4] = {};

    // Per-mr A row pointers (fragment: row = l&15, kgrp = l>>4, 8 contiguous k)
    const float* arow[4];
    #pragma unroll
    for (int mr = 0; mr < 4; ++mr)
        arow[mr] = V + (size_t)(m_base + wm * 64 + mr * 16 + (lane & 15)) * Dd + ((lane >> 4) * 8);

    // stage: contiguous 16KB copy (pre-swizzled in ws)
    auto stage = [&](int buf, int kb) {
        const uint4* src = (const uint4*)(wsChunk + (size_t)kb * 8192);
        uint4* dst = (uint4*)(&btile[buf][0]);
        dst[t] = src[t];
        dst[t + 512] = src[t + 512];
    };

    stage(0, 0);
    __syncthreads();

    int cur = 0;
    for (int kb = 0; kb < 24; ++kb) {
        if (kb + 1 < 24) stage(cur ^ 1, kb + 1);

        // B fragments from LDS (swizzled ds_read_b128)
        short8 bfr[4];
        #pragma unroll
        for (int nr = 0; nr < 4; ++nr) {
            int cl = wn * 64 + nr * 16 + (lane & 15);
            int kgrp = lane >> 4;
            int off = cl * 64 + ((kgrp ^ ((cl >> 1) & 3)) << 4); // bytes
            bfr[nr] = *(const short8*)((const char*)&btile[cur][0] + off);
        }

        // A fragments: load f32x8, convert, 4 MFMAs each
        #pragma unroll
        for (int mr = 0; mr < 4; ++mr) {
            const float4* p = (const float4*)(arow[mr] + kb * 32);
            float4 f0 = p[0];
            float4 f1 = p[1];
            short8 a;
            a[0] = f2bf(f0.x); a[1] = f2bf(f0.y); a[2] = f2bf(f0.z); a[3] = f2bf(f0.w);
            a[4] = f2bf(f1.x); a[5] = f2bf(f1.y); a[6] = f2bf(f1.z); a[7] = f2bf(f1.w);
            #pragma unroll
            for (int nr = 0; nr < 4; ++nr)
                acc[mr][nr] = __builtin_amdgcn_mfma_f32_16x16x32_bf16(a, bfr[nr], acc[mr][nr], 0, 0, 0);
        }

        __syncthreads();
        cur ^= 1;
    }

    // Epilogue: out[m,n] = scale(b,s) * (acc + bv[n]); C/D: col=lane&15, row=(lane>>4)*4+reg
    float bvv[4];
    #pragma unroll
    for (int nr = 0; nr < 4; ++nr)
        bvv[nr] = bv[nt * 256 + wn * 64 + nr * 16 + (lane & 15)];

    int ncol0 = nt * 256 + wn * 64 + (lane & 15);
    #pragma unroll
    for (int mr = 0; mr < 4; ++mr) {
        #pragma unroll
        for (int rg = 0; rg < 4; ++rg) {
            int m = m_base + wm * 64 + mr * 16 + ((lane >> 4) << 2) + rg;
            int b = m / 261;
            int s = m - b * 261;
            float h = hot[b];
            float scale = (s < IMG) ? h : (1.0f - h);
            float* orow = out + (size_t)m * OUTn + ncol0;
            #pragma unroll
            for (int nr = 0; nr < 4; ++nr)
                orow[nr * 16] = scale * (acc[mr][nr][rg] + bvv[nr]);
        }
    }
}

extern "C" void kernel_launch(void* const* d_in, const int* in_sizes, int n_in,
                              void* d_out, int out_size, void* d_ws, size_t ws_size,
                              hipStream_t stream) {
    const float* Q   = (const float*)d_in[0];
    const float* K   = (const float*)d_in[1];
    const float* V   = (const float*)d_in[2];
    const float* Wq  = (const float*)d_in[3];
    const float* bq  = (const float*)d_in[4];
    const float* Wk  = (const float*)d_in[5];
    const float* bk  = (const float*)d_in[6];
    const float* Wsw = (const float*)d_in[7];
    const float* bsw = (const float*)d_in[8];
    const float* Wv  = (const float*)d_in[9];
    const float* bv  = (const float*)d_in[10];

    float* out = (float*)d_out;
    char* ws = (char*)d_ws;
    float* u   = (float*)(ws + WS_U);
    float* c   = (float*)(ws + WS_C);
    float* hot = (float*)(ws + WS_HOT);
    unsigned short* wsB = (unsigned short*)(ws + WS_WB);

    hipLaunchKernelGGL(wv_convert, dim3((OUTn * Dd + 255) / 256), dim3(256), 0, stream, Wv, wsB);
    hipLaunchKernelGGL(qt_u_kernel, dim3(Bn), dim3(256), 0, stream, Q, Wq, bq, Wk, bk, u, c);
    hipLaunchKernelGGL(scores_kernel, dim3(Bn), dim3(512), 0, stream,
                       K, u, c, Wsw, bsw, out + CTX_ELEMS, hot);
    hipLaunchKernelGGL(ctx_gemm, dim3((Mrows / 128) * 2), dim3(512), 0, stream, V, wsB, bv, hot, out);
}